// Round 12
// baseline (198.584 us; speedup 1.0000x reference)
//
#include <hip/hip_runtime.h>

typedef __attribute__((ext_vector_type(4))) int i32x4;

// ---------------------------------------------------------------------------
// Helpers
// ---------------------------------------------------------------------------
__device__ __forceinline__ void gload_lds16(const void* g, void* l) {
  // async global->LDS, 16B/lane. LDS dest must be wave-uniform base + lane*16.
  __builtin_amdgcn_global_load_lds((const __attribute__((address_space(1))) void*)g,
                                   (__attribute__((address_space(3))) void*)l,
                                   16, 0, 0);
}

#define BARRIER() __builtin_amdgcn_s_barrier()
#define VMCNT8()  asm volatile("s_waitcnt vmcnt(8)" ::: "memory")
#define VMCNT4()  asm volatile("s_waitcnt vmcnt(4)" ::: "memory")
#define VMCNT0()  asm volatile("s_waitcnt vmcnt(0)" ::: "memory")

// ---------------------------------------------------------------------------
// Fused quantize f32 -> int8 for both x and w (round-half-even, clamp +-127)
// ---------------------------------------------------------------------------
__global__ void quant_both_kernel(const float* __restrict__ x,
                                  const float* __restrict__ w,
                                  signed char* __restrict__ qx,
                                  signed char* __restrict__ qw,
                                  const float* __restrict__ amax_x,
                                  const float* __restrict__ amax_w,
                                  int nx4, int nw4) {
  const float sx = 127.0f / amax_x[0];
  const float sw = 127.0f / amax_w[0];
  int i = blockIdx.x * blockDim.x + threadIdx.x;
  const int stride = gridDim.x * blockDim.x;
  const int ntot = nx4 + nw4;
  for (; i < ntot; i += stride) {
    const bool isx = i < nx4;
    const float4* src = isx ? (const float4*)x : (const float4*)w;
    int* dst = isx ? (int*)qx : (int*)qw;
    const int j = isx ? i : i - nx4;
    const float s = isx ? sx : sw;
    float4 v = src[j];
    int q0 = (int)rintf(fminf(fmaxf(v.x * s, -127.0f), 127.0f));
    int q1 = (int)rintf(fminf(fmaxf(v.y * s, -127.0f), 127.0f));
    int q2 = (int)rintf(fminf(fmaxf(v.z * s, -127.0f), 127.0f));
    int q3 = (int)rintf(fminf(fmaxf(v.w * s, -127.0f), 127.0f));
    dst[j] = (q0 & 255) | ((q1 & 255) << 8) | ((q2 & 255) << 16) | ((q3 & 255) << 24);
  }
}

// ---------------------------------------------------------------------------
// 256x256 int8 GEMM, 64-MFMA-per-barrier K-loop (AITER-shaped), 160 KiB LDS.
// out[N,M] = dequant(qx[N,K] . qw[M,K]^T) + bias
// 512 thr = 8 waves (2M x 4N), per-wave 128x64, mfma_i32_16x16x64_i8, BK=128.
// LDS: A triple-buffer (3 x 32 KiB) + B double-buffer (2 x 32 KiB) = 160 KiB.
// Per K-tile: {RD B(8)+A-m0(8); STAGE A(t+2)->Ab[(t+2)%3]; 32 MFMA;
//              RD A-m1(8); 32 MFMA; BARRIER; STAGE B(t+2)->Bb[t&1];
//              vmcnt(8); BARRIER}  -- 2 barriers + 1 counted gate per tile,
// NO lgkmcnt(0): compiler's counted lgkm waits interleave reads under MFMA.
// A-triple => A staging never hits a buffer with outstanding reads.
// Swizzle: chunk' = chunk ^ (row&7), inverse on global source (rule #21),
// forward on ds_read. Measured 0 conflicts in this exact read pattern.
// ---------------------------------------------------------------------------
__global__ __launch_bounds__(512, 2) void gemm_i8_big(
    const signed char* __restrict__ qx,   // [N,K]
    const signed char* __restrict__ qw,   // [M,K]
    const float* __restrict__ bias,       // [M]
    const float* __restrict__ amax_x,
    const float* __restrict__ amax_w,
    float* __restrict__ out,              // [N,M]
    int N, int M, int K) {
  constexpr int BKB = 128;  // K bytes per tile

  __shared__ signed char Ab[3][32768];
  __shared__ signed char Bb[2][32768];

  const int tid  = threadIdx.x;
  const int lane = tid & 63;
  const int wid  = tid >> 6;
  const int wm   = wid >> 2;   // 0..1
  const int wn   = wid & 3;    // 0..3
  const int l15  = lane & 15;
  const int l4   = lane >> 4;

  // bijective XCD-aware block swizzle (nwg = 512, divisible by 8)
  const int nbn = M >> 8;                      // 16
  const int nwg = (N >> 8) * nbn;              // 512
  const int cpx = nwg >> 3;
  const int swz = (blockIdx.x & 7) * cpx + (blockIdx.x >> 3);
  const int rowBase = (swz / nbn) << 8;
  const int colBase = (swz % nbn) << 8;

  // staging source pointers: thread t covers slots {h*1024 + L*512 + t};
  // logical (row = slot>>3, c = (slot&7) ^ (row&7)); LDS dest stays linear.
  const signed char* sA[2][2];
  const signed char* sB[2][2];
#pragma unroll
  for (int h = 0; h < 2; ++h)
#pragma unroll
    for (int L = 0; L < 2; ++L) {
      const int slot = h * 1024 + L * 512 + tid;
      const int row  = slot >> 3;
      const int c    = (slot & 7) ^ (row & 7);
      sA[h][L] = qx + (size_t)(rowBase + row) * K + c * 16;
      sB[h][L] = qw + (size_t)(colBase + row) * K + c * 16;
    }

#define STAGE_A(P, kt)                                                   \
  {                                                                      \
    gload_lds16(sA[0][0] + (kt) * BKB, Ab[P] + tid * 16);                \
    gload_lds16(sA[0][1] + (kt) * BKB, Ab[P] + 8192 + tid * 16);         \
    gload_lds16(sA[1][0] + (kt) * BKB, Ab[P] + 16384 + tid * 16);        \
    gload_lds16(sA[1][1] + (kt) * BKB, Ab[P] + 24576 + tid * 16);        \
  }
#define STAGE_B(P, kt)                                                   \
  {                                                                      \
    gload_lds16(sB[0][0] + (kt) * BKB, Bb[P] + tid * 16);                \
    gload_lds16(sB[0][1] + (kt) * BKB, Bb[P] + 8192 + tid * 16);         \
    gload_lds16(sB[1][0] + (kt) * BKB, Bb[P] + 16384 + tid * 16);        \
    gload_lds16(sB[1][1] + (kt) * BKB, Bb[P] + 24576 + tid * 16);        \
  }

  // fragment-read addressing (row&7 == l15&7 since frag bases are mult of 16)
  const int ck0 = ((l4) ^ (l15 & 7)) * 16;       // ks=0 chunk offset
  const int ck1 = ((4 + l4) ^ (l15 & 7)) * 16;   // ks=1
  const int aRow0 = (wm * 128 + l15) * 128;
  const int bRow0 = (wn * 64 + l15) * 128;

  i32x4 acc[8][4] = {{{0}}};
  i32x4 af[4][2];
  i32x4 bf[4][2];

#define RD_B(PB)                                                            \
  {                                                                         \
    _Pragma("unroll") for (int nj = 0; nj < 4; ++nj) {                      \
      bf[nj][0] = *(const i32x4*)(Bb[PB] + bRow0 + nj * 2048 + ck0);        \
      bf[nj][1] = *(const i32x4*)(Bb[PB] + bRow0 + nj * 2048 + ck1);        \
    }                                                                       \
  }
#define RD_A(PA, mh)                                                        \
  {                                                                         \
    _Pragma("unroll") for (int q = 0; q < 4; ++q) {                         \
      af[q][0] = *(const i32x4*)(Ab[PA] + aRow0 + ((mh)*4 + q) * 2048 + ck0); \
      af[q][1] = *(const i32x4*)(Ab[PA] + aRow0 + ((mh)*4 + q) * 2048 + ck1); \
    }                                                                       \
  }
#define MFMAH(mb)                                                           \
  {                                                                         \
    __builtin_amdgcn_s_setprio(1);                                          \
    _Pragma("unroll") for (int mi = 0; mi < 4; ++mi)                        \
        _Pragma("unroll") for (int nj = 0; nj < 4; ++nj)                    \
            _Pragma("unroll") for (int ks = 0; ks < 2; ++ks)                \
                acc[(mb) + mi][nj] = __builtin_amdgcn_mfma_i32_16x16x64_i8( \
                    af[mi][ks], bf[nj][ks], acc[(mb) + mi][nj], 0, 0, 0);   \
    __builtin_amdgcn_s_setprio(0);                                          \
  }

  const int T = K / BKB;  // 32 K-tiles

  // prologue: A0->Ab[0], A1->Ab[1], B0->Bb[0], B1->Bb[1] (16 loads).
  // vmcnt(4): A0,A1,B0 complete for every wave; B1's 4 float. Barrier publishes.
  STAGE_A(0, 0);
  STAGE_A(1, 1);
  STAGE_B(0, 0);
  STAGE_B(1, 1);
  VMCNT4();
  BARRIER();

  int pa = 0;   // A read buffer  = t%3
  int ps = 2;   // A stage buffer = (t+2)%3
  for (int t = 0; t < T; ++t) {
    const int pb = t & 1;
    const int ktn = (t + 2 < T) ? t + 2 : T - 1;  // clamped (stale, never read)

    RD_B(pb);          // 8 ds_read_b128 (buffer published at prev barrier)
    RD_A(pa, 0);       // 8
    STAGE_A(ps, ktn);  // 4 gloads -> Ab[(t+2)%3]: last read at t-1, published
    MFMAH(0);          // 32 MFMA (compiler interleaves counted lgkm waits)
    RD_A(pa, 1);       // 8 (WAR on af, compiler-ordered)
    MFMAH(4);          // 32 MFMA
    BARRIER();         // publish: all waves' reads of Ab[pa], Bb[pb] done
    STAGE_B(pb, ktn);  // 4 gloads into the just-retired B buffer
    VMCNT8();          // retire prev iter's 8 loads (tile t+1); keep this iter's 8
    BARRIER();         // publish tile t+1 for next iter

    pa = (pa == 2) ? 0 : pa + 1;
    ps = (ps == 2) ? 0 : ps + 1;
  }

  VMCNT0();  // drain clamped tail stages before kernel end

  // epilogue: dequant + bias. C/D: col = lane&15, row = (lane>>4)*4 + reg
  const float dq = amax_x[0] * amax_w[0] * (1.0f / (127.0f * 127.0f));
#pragma unroll
  for (int nj = 0; nj < 4; ++nj) {
    const int col = colBase + wn * 64 + nj * 16 + l15;
    const float bv = bias[col];
#pragma unroll
    for (int mi = 0; mi < 8; ++mi) {
      const int row = rowBase + wm * 128 + mi * 16 + l4 * 4;
#pragma unroll
      for (int r = 0; r < 4; ++r)
        out[(size_t)(row + r) * M + col] = (float)acc[mi][nj][r] * dq + bv;
    }
  }
#undef STAGE_A
#undef STAGE_B
#undef RD_A
#undef RD_B
#undef MFMAH
}

// ---------------------------------------------------------------------------
// Launch
// ---------------------------------------------------------------------------
extern "C" void kernel_launch(void* const* d_in, const int* in_sizes, int n_in,
                              void* d_out, int out_size, void* d_ws, size_t ws_size,
                              hipStream_t stream) {
  const float* x      = (const float*)d_in[0];
  const float* w      = (const float*)d_in[1];
  const float* bias   = (const float*)d_in[2];
  const float* amax_x = (const float*)d_in[3];
  const float* amax_w = (const float*)d_in[4];
  float* out = (float*)d_out;

  const int M = in_sizes[2];                    // 4096
  const int K = in_sizes[1] / M;                // 4096
  const int N = (int)((long)in_sizes[0] / K);   // 8192

  signed char* qx = (signed char*)d_ws;         // [N,K] int8
  signed char* qw = qx + (size_t)N * K;         // [M,K] int8

  const int nx4 = N * (K / 4);
  const int nw4 = M * (K / 4);
  quant_both_kernel<<<2048, 256, 0, stream>>>(x, w, qx, qw, amax_x, amax_w,
                                              nx4, nw4);

  const int nwg = (N / 256) * (M / 256);        // 512
  gemm_i8_big<<<nwg, 512, 0, stream>>>(qx, qw, bias, amax_x, amax_w, out,
                                       N, M, K);
}

// Round 13
// 190.128 us; speedup vs baseline: 1.0445x; 1.0445x over previous
//
#include <hip/hip_runtime.h>

typedef __attribute__((ext_vector_type(4))) int i32x4;

// ---------------------------------------------------------------------------
// Helpers
// ---------------------------------------------------------------------------
__device__ __forceinline__ void gload_lds16(const void* g, void* l) {
  // async global->LDS, 16B/lane. LDS dest must be wave-uniform base + lane*16.
  __builtin_amdgcn_global_load_lds((const __attribute__((address_space(1))) void*)g,
                                   (__attribute__((address_space(3))) void*)l,
                                   16, 0, 0);
}

#define BARRIER() __builtin_amdgcn_s_barrier()
#define LGKM0()   asm volatile("s_waitcnt lgkmcnt(0)" ::: "memory")
#define VMCNT4()  asm volatile("s_waitcnt vmcnt(4)" ::: "memory")

// ---------------------------------------------------------------------------
// Fused quantize f32 -> int8 for both x and w (round-half-even, clamp +-127)
// ---------------------------------------------------------------------------
__global__ void quant_both_kernel(const float* __restrict__ x,
                                  const float* __restrict__ w,
                                  signed char* __restrict__ qx,
                                  signed char* __restrict__ qw,
                                  const float* __restrict__ amax_x,
                                  const float* __restrict__ amax_w,
                                  int nx4, int nw4) {
  const float sx = 127.0f / amax_x[0];
  const float sw = 127.0f / amax_w[0];
  int i = blockIdx.x * blockDim.x + threadIdx.x;
  const int stride = gridDim.x * blockDim.x;
  const int ntot = nx4 + nw4;
  for (; i < ntot; i += stride) {
    const bool isx = i < nx4;
    const float4* src = isx ? (const float4*)x : (const float4*)w;
    int* dst = isx ? (int*)qx : (int*)qw;
    const int j = isx ? i : i - nx4;
    const float s = isx ? sx : sw;
    float4 v = src[j];
    int q0 = (int)rintf(fminf(fmaxf(v.x * s, -127.0f), 127.0f));
    int q1 = (int)rintf(fminf(fmaxf(v.y * s, -127.0f), 127.0f));
    int q2 = (int)rintf(fminf(fmaxf(v.z * s, -127.0f), 127.0f));
    int q3 = (int)rintf(fminf(fmaxf(v.w * s, -127.0f), 127.0f));
    dst[j] = (q0 & 255) | ((q1 & 255) << 8) | ((q2 & 255) << 16) | ((q3 & 255) << 24);
  }
}

// ---------------------------------------------------------------------------
// 256x256 8-phase int8 GEMM (verified round-3 kernel, verbatim — best of 8
// structural variants tested this session; 138.5 us x3 reproductions).
// out[N,M] = dequant(qx[N,K] . qw[M,K]^T) + bias
// 512 thr = 8 waves (2M x 4N), per-wave 128x64, mfma_i32_16x16x64_i8,
// BK=128 int8 (2 k-subtiles of 64), LDS 2dbuf x (A,B) x [256][128B] = 128 KiB.
// Swizzle: 16B-chunk' = chunk ^ (row&7); applied to global SOURCE on staging
// (LDS dest linear, rule #21) and to the ds_read address. Measured 0 conflict.
// Gates: vmcnt(4) BEFORE the trailing barriers of P4/P8 (all waves drain,
// then barrier publishes) — counted, never 0 in the main loop.
// ---------------------------------------------------------------------------
__global__ __launch_bounds__(512, 2) void gemm_i8_8p(
    const signed char* __restrict__ qx,   // [N,K]
    const signed char* __restrict__ qw,   // [M,K]
    const float* __restrict__ bias,       // [M]
    const float* __restrict__ amax_x,
    const float* __restrict__ amax_w,
    float* __restrict__ out,              // [N,M]
    int N, int M, int K) {
  constexpr int BKB = 128;  // K bytes per tile

  __shared__ signed char lds[4][256 * 128];  // [A0,B0,A1,B1], 32 KiB each

  const int tid  = threadIdx.x;
  const int lane = tid & 63;
  const int wid  = tid >> 6;
  const int wm   = wid >> 2;   // 0..1
  const int wn   = wid & 3;    // 0..3
  const int l15  = lane & 15;
  const int l4   = lane >> 4;

  // bijective XCD-aware block swizzle (nwg = 512, divisible by 8)
  const int nbn = M >> 8;                      // 16
  const int nwg = (N >> 8) * nbn;              // 512
  const int cpx = nwg >> 3;
  const int swz = (blockIdx.x & 7) * cpx + (blockIdx.x >> 3);
  const int rowBase = (swz / nbn) << 8;
  const int colBase = (swz % nbn) << 8;

  // staging source pointers: thread t covers slots {h*1024 + L*512 + t};
  // logical (row = slot>>3, c = (slot&7) ^ (row&7)); LDS dest stays linear.
  const signed char* sA[2][2];
  const signed char* sB[2][2];
#pragma unroll
  for (int h = 0; h < 2; ++h)
#pragma unroll
    for (int L = 0; L < 2; ++L) {
      const int slot = h * 1024 + L * 512 + tid;
      const int row  = slot >> 3;
      const int c    = (slot & 7) ^ (row & 7);
      sA[h][L] = qx + (size_t)(rowBase + row) * K + c * 16;
      sB[h][L] = qw + (size_t)(colBase + row) * K + c * 16;
    }

  signed char* A0 = lds[0];
  signed char* B0 = lds[1];
  signed char* A1 = lds[2];
  signed char* B1 = lds[3];

#define STAGE(dst, src, h, kt)                                             \
  do {                                                                     \
    gload_lds16(src[h][0] + (kt) * BKB, (dst) + (h)*16384 + tid * 16);     \
    gload_lds16(src[h][1] + (kt) * BKB, (dst) + (h)*16384 + 8192 + tid * 16); \
  } while (0)

  // fragment-read addressing (row&7 == l15&7 since frag bases are mult of 16)
  const int ck0 = ((l4) ^ (l15 & 7)) * 16;       // ks=0 chunk offset
  const int ck1 = ((4 + l4) ^ (l15 & 7)) * 16;   // ks=1
  const int aRow0 = (wm * 128 + l15) * 128;
  const int bRow0 = (wn * 64 + l15) * 128;

  i32x4 acc[8][4] = {{{0}}};
  i32x4 af[4][2];
  i32x4 bf[4][2];

#define RDA(R, mb)                                                          \
  {                                                                         \
    _Pragma("unroll") for (int mi = 0; mi < 4; ++mi) {                      \
      af[mi][0] = *(const i32x4*)((R) + aRow0 + ((mb) + mi) * 2048 + ck0);  \
      af[mi][1] = *(const i32x4*)((R) + aRow0 + ((mb) + mi) * 2048 + ck1);  \
    }                                                                       \
  }
#define RDB(R, nb)                                                          \
  {                                                                         \
    _Pragma("unroll") for (int nj = 0; nj < 2; ++nj) {                      \
      bf[(nb) + nj][0] = *(const i32x4*)((R) + bRow0 + ((nb) + nj) * 2048 + ck0); \
      bf[(nb) + nj][1] = *(const i32x4*)((R) + bRow0 + ((nb) + nj) * 2048 + ck1); \
    }                                                                       \
  }
#define MFMAQ(mb, nb)                                                       \
  {                                                                         \
    _Pragma("unroll") for (int mi = 0; mi < 4; ++mi)                        \
        _Pragma("unroll") for (int nj = 0; nj < 2; ++nj)                    \
            _Pragma("unroll") for (int ks = 0; ks < 2; ++ks)                \
                acc[(mb) + mi][(nb) + nj] = __builtin_amdgcn_mfma_i32_16x16x64_i8( \
                    af[mi][ks], bf[(nb) + nj][ks], acc[(mb) + mi][(nb) + nj], 0, 0, 0); \
  }

  const int T = K / BKB;  // 32 K-tiles

  // prologue: tile0 -> A0/B0 (8 loads), tile1's B -> B1 (4 loads).
  // Gate tile0: every wave drains to <=4 outstanding (A0,B0 done; B1 may
  // float), THEN barrier -> all waves' A0/B0 loads are in LDS.
  STAGE(B0, sB, 0, 0); STAGE(B0, sB, 1, 0);
  STAGE(A0, sA, 0, 0); STAGE(A0, sA, 1, 0);
  STAGE(B1, sB, 0, 1); STAGE(B1, sB, 1, 1);
  VMCNT4();
  BARRIER();

  for (int it = 0; it < T / 2; ++it) {
    const int k1 = 2 * it + 1;
    const int k2 = (2 * it + 2 < T) ? 2 * it + 2 : T - 1;  // clamped (stale, never read)
    const int k3 = (2 * it + 3 < T) ? 2 * it + 3 : T - 1;

    // P1: read A0[M0]+B0[N0] (gated at prev end-P8 / prologue); stage A1h0 <- t+1
    RDA(A0, 0); RDB(B0, 0);
    STAGE(A1, sA, 0, k1);
    BARRIER(); LGKM0();
    __builtin_amdgcn_s_setprio(1); MFMAQ(0, 0); __builtin_amdgcn_s_setprio(0);
    BARRIER();

    // P2: read B0[N1]; stage A1h1 <- t+1
    RDB(B0, 2);
    STAGE(A1, sA, 1, k1);
    BARRIER(); LGKM0();
    __builtin_amdgcn_s_setprio(1); MFMAQ(0, 2); __builtin_amdgcn_s_setprio(0);
    BARRIER();

    // P3: read A0[M1]; stage B0h0 <- t+2 (B0 reads all done by P2's trailing barrier)
    RDA(A0, 4);
    STAGE(B0, sB, 0, k2);
    BARRIER(); LGKM0();
    __builtin_amdgcn_s_setprio(1); MFMAQ(4, 0); __builtin_amdgcn_s_setprio(0);
    BARRIER();

    // P4: stage B0h1 <- t+2. GATE tile t+1 (A1 from P1/P2, B1 from prev P7/P8):
    // vmcnt(4) leaves only P3/P4's B0 loads in flight; barrier publishes.
    STAGE(B0, sB, 1, k2);
    BARRIER(); LGKM0();
    __builtin_amdgcn_s_setprio(1); MFMAQ(4, 2); __builtin_amdgcn_s_setprio(0);
    VMCNT4();
    BARRIER();

    // P5: read A1[M0]+B1[N0] (gated at end-P4); stage A0h0 <- t+2
    RDA(A1, 0); RDB(B1, 0);
    STAGE(A0, sA, 0, k2);
    BARRIER(); LGKM0();
    __builtin_amdgcn_s_setprio(1); MFMAQ(0, 0); __builtin_amdgcn_s_setprio(0);
    BARRIER();

    // P6: read B1[N1]; stage A0h1 <- t+2
    RDB(B1, 2);
    STAGE(A0, sA, 1, k2);
    BARRIER(); LGKM0();
    __builtin_amdgcn_s_setprio(1); MFMAQ(0, 2); __builtin_amdgcn_s_setprio(0);
    BARRIER();

    // P7: read A1[M1]; stage B1h0 <- t+3
    RDA(A1, 4);
    STAGE(B1, sB, 0, k3);
    BARRIER(); LGKM0();
    __builtin_amdgcn_s_setprio(1); MFMAQ(4, 0); __builtin_amdgcn_s_setprio(0);
    BARRIER();

    // P8: stage B1h1 <- t+3. GATE tile t+2's A0/B0 (P3-P6 loads):
    // vmcnt(4) leaves only P7/P8's B1 loads in flight; barrier publishes.
    STAGE(B1, sB, 1, k3);
    BARRIER(); LGKM0();
    __builtin_amdgcn_s_setprio(1); MFMAQ(4, 2); __builtin_amdgcn_s_setprio(0);
    VMCNT4();
    BARRIER();
  }

  // epilogue: dequant + bias. C/D: col = lane&15, row = (lane>>4)*4 + reg
  const float dq = amax_x[0] * amax_w[0] * (1.0f / (127.0f * 127.0f));
#pragma unroll
  for (int nj = 0; nj < 4; ++nj) {
    const int col = colBase + wn * 64 + nj * 16 + l15;
    const float bv = bias[col];
#pragma unroll
    for (int mi = 0; mi < 8; ++mi) {
      const int row = rowBase + wm * 128 + mi * 16 + l4 * 4;
#pragma unroll
      for (int r = 0; r < 4; ++r)
        out[(size_t)(row + r) * M + col] = (float)acc[mi][nj][r] * dq + bv;
    }
  }
#undef STAGE
#undef RDA
#undef RDB
#undef MFMAQ
}

// ---------------------------------------------------------------------------
// Launch
// ---------------------------------------------------------------------------
extern "C" void kernel_launch(void* const* d_in, const int* in_sizes, int n_in,
                              void* d_out, int out_size, void* d_ws, size_t ws_size,
                              hipStream_t stream) {
  const float* x      = (const float*)d_in[0];
  const float* w      = (const float*)d_in[1];
  const float* bias   = (const float*)d_in[2];
  const float* amax_x = (const float*)d_in[3];
  const float* amax_w = (const float*)d_in[4];
  float* out = (float*)d_out;

  const int M = in_sizes[2];                    // 4096
  const int K = in_sizes[1] / M;                // 4096
  const int N = (int)((long)in_sizes[0] / K);   // 8192

  signed char* qx = (signed char*)d_ws;         // [N,K] int8
  signed char* qw = qx + (size_t)N * K;         // [M,K] int8

  const int nx4 = N * (K / 4);
  const int nw4 = M * (K / 4);
  quant_both_kernel<<<2048, 256, 0, stream>>>(x, w, qx, qw, amax_x, amax_w,
                                              nx4, nw4);

  const int nwg = (N / 256) * (M / 256);        // 512
  gemm_i8_8p<<<nwg, 512, 0, stream>>>(qx, qw, bias, amax_x, amax_w, out,
                                      N, M, K);
}